// Round 3
// baseline (740.799 us; speedup 1.0000x reference)
//
#include <hip/hip_runtime.h>
#include <hip/hip_bf16.h>

// Attention with softmax over the QUERY axis (axis=1):
//   attn[:,q,k] = exp(S[q,k]) / Z[k],  Z[k] = sum_q exp(S[q,k])
//   out = expS @ (diag(1/Z) V)   -- rZ folded into V by k_scalev.
// B=2, N=8192, D=256. All matmuls via mfma_f32_16x16x32_bf16.
// R3: K/V streamed global->reg (L2-resident), LDS only for P (dbuf, 1 barrier/kt).

#define N_ 8192
#define SCALE 0.0625f

typedef __attribute__((ext_vector_type(8))) short short8;
typedef __attribute__((ext_vector_type(4))) float f32x4;
typedef __attribute__((ext_vector_type(4))) unsigned short ushort4_t;

__device__ inline unsigned short f2bf(float f) {
    unsigned int x = __float_as_uint(f);
    unsigned int r = (x + 0x7fffu + ((x >> 16) & 1u)) >> 16;  // RNE
    return (unsigned short)r;
}

__device__ inline short8 ldg8(const unsigned short* p) {
    return *reinterpret_cast<const short8*>(p);
}

__device__ inline short8 cvt8(const float* p) {
    float4 a = *(const float4*)p;
    float4 b = *(const float4*)(p + 4);
    short8 r;
    r[0] = (short)f2bf(a.x); r[1] = (short)f2bf(a.y);
    r[2] = (short)f2bf(a.z); r[3] = (short)f2bf(a.w);
    r[4] = (short)f2bf(b.x); r[5] = (short)f2bf(b.y);
    r[6] = (short)f2bf(b.z); r[7] = (short)f2bf(b.w);
    return r;
}

__device__ inline f32x4 mfma16(short8 a, short8 b, f32x4 c) {
    return __builtin_amdgcn_mfma_f32_16x16x32_bf16(a, b, c, 0, 0, 0);
}

__device__ inline float bf2f(unsigned short u) {
    return __uint_as_float(((unsigned)u) << 16);
}

#define WAIT_LGKM0() asm volatile("s_waitcnt lgkmcnt(0)" ::: "memory")
#define BARRIER()    __builtin_amdgcn_s_barrier()

// ---------------------------------------------------------------------------
// Kernel 0: W (3 x 256x256 f32) -> Wb (768x256 bf16), concatenated Q|K|V.
// ---------------------------------------------------------------------------
__global__ __launch_bounds__(256) void k_cvtw(
    const float* __restrict__ Wq, const float* __restrict__ Wk,
    const float* __restrict__ Wv, unsigned short* __restrict__ Wb)
{
    int t = blockIdx.x * 256 + threadIdx.x;     // 24576 threads x 8 elems
    int e8 = t * 8;
    const float* src = (e8 < 65536) ? Wq + e8
                     : (e8 < 131072) ? Wk + (e8 - 65536)
                                     : Wv + (e8 - 131072);
    *reinterpret_cast<short8*>(Wb + e8) = cvt8(src);
}

// ---------------------------------------------------------------------------
// Kernel 1: QKV projection, no LDS. Grid 256 blocks (row-tiles of 64), 512 thr.
// Each wave: 32 rows (2 frags, converted once) x 192 cols (12 frags).
// Q,K -> [b*N+r][256] bf16; V -> transposed Vt[b][e][n] bf16.
// ---------------------------------------------------------------------------
__global__ __launch_bounds__(512) void k_proj(
    const float* __restrict__ x, const unsigned short* __restrict__ Wb,
    unsigned short* __restrict__ Qb, unsigned short* __restrict__ Kb,
    unsigned short* __restrict__ Vt)
{
    int rb = blockIdx.x;
    int tid = threadIdx.x, w = tid >> 6, lane = tid & 63;
    int lr = lane & 15, lg = lane >> 4;
    int wqs = w >> 2, wcs = w & 3;
    int r0 = rb * 64 + wqs * 32;

    short8 qfr[2][8];
#pragma unroll
    for (int qf = 0; qf < 2; ++qf)
#pragma unroll
        for (int ks = 0; ks < 8; ++ks)
            qfr[qf][ks] = cvt8(x + (size_t)(r0 + qf * 16 + lr) * 256 + ks * 32 + lg * 8);

    f32x4 acc[2][12] = {};
#pragma unroll
    for (int ks = 0; ks < 8; ++ks) {
#pragma unroll
        for (int cf = 0; cf < 12; ++cf) {
            int e = wcs * 192 + cf * 16 + lr;
            short8 bfr = ldg8(Wb + (size_t)e * 256 + ks * 32 + lg * 8);
            acc[0][cf] = mfma16(qfr[0][ks], bfr, acc[0][cf]);
            acc[1][cf] = mfma16(qfr[1][ks], bfr, acc[1][cf]);
        }
    }

#pragma unroll
    for (int qf = 0; qf < 2; ++qf)
#pragma unroll
        for (int cf = 0; cf < 12; ++cf) {
            int e0c = wcs * 192 + cf * 16;
            int mat = e0c >> 8;               // uniform across lanes
            int ecol = (e0c & 255) + lr;
            int rbase = r0 + qf * 16 + lg * 4;
            if (mat < 2) {
                unsigned short* dst = (mat == 0) ? Qb : Kb;
#pragma unroll
                for (int r = 0; r < 4; ++r)
                    dst[(size_t)(rbase + r) * 256 + ecol] = f2bf(acc[qf][cf][r]);
            } else {
                int bidx = rbase >> 13, nr = rbase & 8191;
                ushort4_t v;
#pragma unroll
                for (int r = 0; r < 4; ++r) v[r] = f2bf(acc[qf][cf][r]);
                *reinterpret_cast<ushort4_t*>(
                    Vt + ((size_t)bidx * 256 + ecol) * 8192 + nr) = v;
            }
        }
}

// ---------------------------------------------------------------------------
// Kernel 2: rZ[b][k] = 1 / sum_q exp(S[q,k]*SCALE). Grid (128 kt, 2 b), 512 thr.
// K-tile frags hoisted to regs once; Q streamed; exp of prev iter covers latency.
// ---------------------------------------------------------------------------
__global__ __launch_bounds__(512) void k_zsum(
    const unsigned short* __restrict__ Qb, const unsigned short* __restrict__ Kb,
    float* __restrict__ rZ)
{
    __shared__ float zred[4][64];
    int kt = blockIdx.x, b = blockIdx.y;
    int tid = threadIdx.x, w = tid >> 6, lane = tid & 63;
    int lr = lane & 15, lg = lane >> 4;
    int wqg = w >> 1, wkh = w & 1;

    short8 kfr[2][8];
#pragma unroll
    for (int kn = 0; kn < 2; ++kn)
#pragma unroll
        for (int ks = 0; ks < 8; ++ks)
            kfr[kn][ks] = ldg8(
                Kb + (size_t)(b * N_ + kt * 64 + wkh * 32 + kn * 16 + lr) * 256
                   + ks * 32 + lg * 8);

    float zk0 = 0.f, zk1 = 0.f;
    f32x4 sp[2][2];
    const unsigned short* q0p = Qb + (size_t)(b * N_ + wqg * 32 + lr) * 256 + lg * 8;
    const unsigned short* q1p = Qb + (size_t)(b * N_ + wqg * 32 + 16 + lr) * 256 + lg * 8;
    const size_t qadv = (size_t)128 * 256;

    for (int it = 0; it < 64; ++it) {
        short8 qf0[8], qf1[8];
#pragma unroll
        for (int ks = 0; ks < 8; ++ks) {
            qf0[ks] = ldg8(q0p + ks * 32);
            qf1[ks] = ldg8(q1p + ks * 32);
        }
        q0p += qadv; q1p += qadv;

        if (it > 0) {
#pragma unroll
            for (int qf = 0; qf < 2; ++qf)
#pragma unroll
                for (int r = 0; r < 4; ++r) {
                    zk0 += __expf(sp[qf][0][r] * SCALE);
                    zk1 += __expf(sp[qf][1][r] * SCALE);
                }
        }

        f32x4 s00 = {}, s01 = {}, s10 = {}, s11 = {};
#pragma unroll
        for (int ks = 0; ks < 8; ++ks) {
            s00 = mfma16(qf0[ks], kfr[0][ks], s00);
            s01 = mfma16(qf0[ks], kfr[1][ks], s01);
            s10 = mfma16(qf1[ks], kfr[0][ks], s10);
            s11 = mfma16(qf1[ks], kfr[1][ks], s11);
        }
        sp[0][0] = s00; sp[0][1] = s01; sp[1][0] = s10; sp[1][1] = s11;
    }
#pragma unroll
    for (int qf = 0; qf < 2; ++qf)
#pragma unroll
        for (int r = 0; r < 4; ++r) {
            zk0 += __expf(sp[qf][0][r] * SCALE);
            zk1 += __expf(sp[qf][1][r] * SCALE);
        }

    zk0 += __shfl_xor(zk0, 16); zk0 += __shfl_xor(zk0, 32);
    zk1 += __shfl_xor(zk1, 16); zk1 += __shfl_xor(zk1, 32);
    if (lg == 0) {
        zred[wqg][wkh * 32 + lr] = zk0;
        zred[wqg][wkh * 32 + 16 + lr] = zk1;
    }
    __syncthreads();
    if (tid < 64) {
        float s = zred[0][tid] + zred[1][tid] + zred[2][tid] + zred[3][tid];
        rZ[(size_t)b * N_ + kt * 64 + tid] = 1.0f / s;
    }
}

// ---------------------------------------------------------------------------
// Kernel 2.5: V' = V * rZ (in place on Vt, bf16).
// ---------------------------------------------------------------------------
__global__ __launch_bounds__(256) void k_scalev(
    unsigned short* __restrict__ Vt, const float* __restrict__ rZ)
{
    int t = blockIdx.x * 256 + threadIdx.x;   // 524288 granules of 8
    int b = t >> 18, g = t & 262143;
    int d = g >> 10, k8 = (g & 1023) * 8;
    unsigned short* p = Vt + ((size_t)b * 256 + d) * 8192 + k8;
    short8 v = *reinterpret_cast<short8*>(p);
    const float* rz = rZ + (size_t)b * 8192 + k8;
    float4 r0 = *(const float4*)rz, r1 = *(const float4*)(rz + 4);
    float rv[8] = {r0.x, r0.y, r0.z, r0.w, r1.x, r1.y, r1.z, r1.w};
    short8 o;
#pragma unroll
    for (int j = 0; j < 8; ++j)
        o[j] = (short)f2bf(bf2f((unsigned short)v[j]) * rv[j]);
    *reinterpret_cast<short8*>(p) = o;
}

// ---------------------------------------------------------------------------
// Kernel 3: out[q,d] = sum_k exp(S[q,k]*SCALE) * V'[k,d].
// Grid (128 qt, 2 b), 512 thr (8 waves). Per wave: 32q; S k-quarter 16k;
// PV d-quarter 64d. K dbuf in regs, V single-buf regs, P dbuf in LDS (2x8KB),
// ONE barrier per kt.
// ---------------------------------------------------------------------------
__global__ __launch_bounds__(512, 2) void k_attn(
    const unsigned short* __restrict__ Qb, const unsigned short* __restrict__ Kb,
    const unsigned short* __restrict__ Vt, float* __restrict__ out)
{
    __shared__ char sP0[8192];
    __shared__ char sP1[8192];
    const int qt = blockIdx.x, b = blockIdx.y;
    const int tid = threadIdx.x, w = tid >> 6, lane = tid & 63;
    const int lr = lane & 15, lg = lane >> 4;
    const int wqs = w >> 2, wq4 = w & 3;
    const int qbase = qt * 64, q0 = wqs * 32;

    // hoist Q: 32 rows x 256 d
    short8 qfr[2][8];
#pragma unroll
    for (int qf = 0; qf < 2; ++qf) {
        const unsigned short* qrow =
            Qb + (size_t)(b * N_ + qbase + q0 + qf * 16 + lr) * 256;
#pragma unroll
        for (int ks = 0; ks < 8; ++ks)
            qfr[qf][ks] = ldg8(qrow + ks * 32 + lg * 8);
    }

    // K stream pointer (this wave's k-quarter, row lr)
    const unsigned short* kptr =
        Kb + (size_t)(b * N_ + wq4 * 16 + lr) * 256 + lg * 8;
    // V pointers per d-frag
    const unsigned short* vptr0 = Vt + ((size_t)(b * 256 + wq4 * 64 +  0 + lr)) * 8192 + lg * 8;
    const unsigned short* vptr1 = Vt + ((size_t)(b * 256 + wq4 * 64 + 16 + lr)) * 8192 + lg * 8;
    const unsigned short* vptr2 = Vt + ((size_t)(b * 256 + wq4 * 64 + 32 + lr)) * 8192 + lg * 8;
    const unsigned short* vptr3 = Vt + ((size_t)(b * 256 + wq4 * 64 + 48 + lr)) * 8192 + lg * 8;

    short8 kfA[8], kfB[8], vfr[8];
    f32x4 acco[2][4] = {};

    // prologue: K(0) -> kfA
#pragma unroll
    for (int ks = 0; ks < 8; ++ks) kfA[ks] = ldg8(kptr + ks * 32);
    kptr += 64 * 256;

#define AITER(PB, KC, KN)                                                     \
    do {                                                                      \
        _Pragma("unroll") for (int ks = 0; ks < 8; ++ks)                      \
            KN[ks] = ldg8(kptr + ks * 32);                                    \
        kptr += 64 * 256;                                                     \
        vfr[0] = ldg8(vptr0); vfr[1] = ldg8(vptr0 + 32); vptr0 += 64;         \
        vfr[2] = ldg8(vptr1); vfr[3] = ldg8(vptr1 + 32); vptr1 += 64;         \
        vfr[4] = ldg8(vptr2); vfr[5] = ldg8(vptr2 + 32); vptr2 += 64;         \
        vfr[6] = ldg8(vptr3); vfr[7] = ldg8(vptr3 + 32); vptr3 += 64;         \
        f32x4 s0 = {0.f, 0.f, 0.f, 0.f}, s1 = {0.f, 0.f, 0.f, 0.f};           \
        __builtin_amdgcn_s_setprio(1);                                        \
        _Pragma("unroll") for (int ks = 0; ks < 8; ++ks) {                    \
            s0 = mfma16(qfr[0][ks], KC[ks], s0);                              \
            s1 = mfma16(qfr[1][ks], KC[ks], s1);                              \
        }                                                                     \
        __builtin_amdgcn_s_setprio(0);                                        \
        _Pragma("unroll") for (int qf = 0; qf < 2; ++qf) {                    \
            f32x4 sv = qf ? s1 : s0;                                          \
            _Pragma("unroll") for (int r = 0; r < 4; ++r) {                   \
                float p = __expf(sv[r] * SCALE);                              \
                int q = q0 + qf * 16 + lg * 4 + r;                            \
                int kcol = wq4 * 16 + lr;                                     \
                int off = (q * 128 + kcol * 2) ^ ((q & 7) << 4);              \
                *reinterpret_cast<unsigned short*>(PB + off) = f2bf(p);       \
            }                                                                 \
        }                                                                     \
        WAIT_LGKM0();                                                         \
        BARRIER();                                                            \
        __builtin_amdgcn_s_setprio(1);                                        \
        _Pragma("unroll") for (int kk = 0; kk < 2; ++kk) {                    \
            short8 pa0, pa1;                                                  \
            {                                                                 \
                int qq = q0 + lr;                                             \
                int offa = (qq * 128 + (kk * 32 + lg * 8) * 2) ^ ((qq & 7) << 4); \
                pa0 = *reinterpret_cast<const short8*>(PB + offa);            \
            }                                                                 \
            {                                                                 \
                int qq = q0 + 16 + lr;                                        \
                int offa = (qq * 128 + (kk * 32 + lg * 8) * 2) ^ ((qq & 7) << 4); \
                pa1 = *reinterpret_cast<const short8*>(PB + offa);            \
            }                                                                 \
            acco[0][0] = mfma16(pa0, vfr[0 + kk], acco[0][0]);                \
            acco[1][0] = mfma16(pa1, vfr[0 + kk], acco[1][0]);                \
            acco[0][1] = mfma16(pa0, vfr[2 + kk], acco[0][1]);                \
            acco[1][1] = mfma16(pa1, vfr[2 + kk], acco[1][1]);                \
            acco[0][2] = mfma16(pa0, vfr[4 + kk], acco[0][2]);                \
            acco[1][2] = mfma16(pa1, vfr[4 + kk], acco[1][2]);                \
            acco[0][3] = mfma16(pa0, vfr[6 + kk], acco[0][3]);                \
            acco[1][3] = mfma16(pa1, vfr[6 + kk], acco[1][3]);                \
        }                                                                     \
        __builtin_amdgcn_s_setprio(0);                                        \
    } while (0)

    for (int kt2 = 0; kt2 < 64; ++kt2) {
        AITER(sP0, kfA, kfB);
        AITER(sP1, kfB, kfA);
    }
#undef AITER

    // epilogue: f32 store
#pragma unroll
    for (int qf = 0; qf < 2; ++qf)
#pragma unroll
        for (int df = 0; df < 4; ++df) {
            int d = wq4 * 64 + df * 16 + lr;
            int q0r = qbase + q0 + qf * 16 + lg * 4;
#pragma unroll
            for (int r = 0; r < 4; ++r)
                out[(size_t)(b * N_ + q0r + r) * 256 + d] = acco[qf][df][r];
        }
}

extern "C" void kernel_launch(void* const* d_in, const int* in_sizes, int n_in,
                              void* d_out, int out_size, void* d_ws, size_t ws_size,
                              hipStream_t stream)
{
    const float* x  = (const float*)d_in[0];
    const float* Wq = (const float*)d_in[1];
    const float* Wk = (const float*)d_in[2];
    const float* Wv = (const float*)d_in[3];

    char* ws = (char*)d_ws;
    unsigned short* Qb = (unsigned short*)(ws);              //  8 MB
    unsigned short* Kb = (unsigned short*)(ws + 8388608);    //  8 MB
    unsigned short* Vt = (unsigned short*)(ws + 16777216);   //  8 MB
    unsigned short* Wb = (unsigned short*)(ws + 25165824);   // 384 KB
    float* rZ          = (float*)(ws + 25559040);            //  64 KB
    float* out = (float*)d_out;

    k_cvtw<<<dim3(96), dim3(256), 0, stream>>>(Wq, Wk, Wv, Wb);
    k_proj<<<dim3(256), dim3(512), 0, stream>>>(x, Wb, Qb, Kb, Vt);
    k_zsum<<<dim3(128, 2), dim3(512), 0, stream>>>(Qb, Kb, rZ);
    k_scalev<<<dim3(2048), dim3(256), 0, stream>>>(Vt, rZ);
    k_attn<<<dim3(128, 2), dim3(512), 0, stream>>>(Qb, Kb, Vt, out);
}

// Round 4
// 497.311 us; speedup vs baseline: 1.4896x; 1.4896x over previous
//
#include <hip/hip_runtime.h>
#include <hip/hip_bf16.h>

// Attention with softmax over the QUERY axis (axis=1):
//   attn[:,q,k] = exp(S[q,k]) / Z[k],  Z[k] = sum_q exp(S[q,k])
//   out = expS @ (diag(1/Z) V)   -- rZ folded into V by k_scalev.
// B=2, N=8192, D=256. All matmuls via mfma_f32_16x16x32_bf16.
// R4: R2 skeleton; k_attn qtile=128 + k-range split (2 blocks) + k_add merge.

#define N_ 8192
#define SCALE 0.0625f

typedef __attribute__((ext_vector_type(8))) short short8;
typedef __attribute__((ext_vector_type(4))) float f32x4;
typedef __attribute__((ext_vector_type(4))) unsigned short ushort4_t;

__device__ inline unsigned short f2bf(float f) {
    unsigned int x = __float_as_uint(f);
    unsigned int r = (x + 0x7fffu + ((x >> 16) & 1u)) >> 16;  // RNE
    return (unsigned short)r;
}

__device__ inline short8 ldg8(const unsigned short* p) {
    return *reinterpret_cast<const short8*>(p);
}

__device__ inline short8 cvt8(const float* p) {
    float4 a = *(const float4*)p;
    float4 b = *(const float4*)(p + 4);
    short8 r;
    r[0] = (short)f2bf(a.x); r[1] = (short)f2bf(a.y);
    r[2] = (short)f2bf(a.z); r[3] = (short)f2bf(a.w);
    r[4] = (short)f2bf(b.x); r[5] = (short)f2bf(b.y);
    r[6] = (short)f2bf(b.z); r[7] = (short)f2bf(b.w);
    return r;
}

__device__ inline f32x4 mfma16(short8 a, short8 b, f32x4 c) {
    return __builtin_amdgcn_mfma_f32_16x16x32_bf16(a, b, c, 0, 0, 0);
}

__device__ inline float bf2f(unsigned short u) {
    return __uint_as_float(((unsigned)u) << 16);
}

typedef __attribute__((address_space(3))) unsigned int lds_u32;
typedef __attribute__((address_space(1))) const unsigned int glb_u32;
__device__ __forceinline__ void gll16(const void* g, void* l) {
    __builtin_amdgcn_global_load_lds((glb_u32*)g, (lds_u32*)l, 16, 0, 0);
}
#define WAIT_VM0()   asm volatile("s_waitcnt vmcnt(0)" ::: "memory")
#define WAIT_LGKM0() asm volatile("s_waitcnt lgkmcnt(0)" ::: "memory")
#define BARRIER()    __builtin_amdgcn_s_barrier()

// ---------------------------------------------------------------------------
// Kernel 1: QKV projection (R2 version, proven).
// ---------------------------------------------------------------------------
__global__ __launch_bounds__(256) void k_proj(
    const float* __restrict__ x, const float* __restrict__ Wq,
    const float* __restrict__ Wk, const float* __restrict__ Wv,
    unsigned short* __restrict__ Qb, unsigned short* __restrict__ Kb,
    unsigned short* __restrict__ Vt)
{
    int rb = blockIdx.x, cb = blockIdx.y;
    int mat = cb >> 2;                 // 0:Q 1:K 2:V
    int e0 = (cb & 3) * 64;
    const float* W = (mat == 0) ? Wq : (mat == 1) ? Wk : Wv;
    int tid = threadIdx.x, w = tid >> 6, lane = tid & 63;
    int lr = lane & 15, lg = lane >> 4;
    int wq = (w >> 1) * 32, wc = (w & 1) * 32;
    int r0 = rb * 64 + wq;

    f32x4 acc[2][2] = {};
    for (int ks = 0; ks < 8; ++ks) {
        int d0 = ks * 32 + lg * 8;
        short8 a0 = cvt8(x + (size_t)(r0 + lr) * 256 + d0);
        short8 a1 = cvt8(x + (size_t)(r0 + 16 + lr) * 256 + d0);
        short8 b0 = cvt8(W + (size_t)(e0 + wc + lr) * 256 + d0);
        short8 b1 = cvt8(W + (size_t)(e0 + wc + 16 + lr) * 256 + d0);
        acc[0][0] = mfma16(a0, b0, acc[0][0]);
        acc[0][1] = mfma16(a0, b1, acc[0][1]);
        acc[1][0] = mfma16(a1, b0, acc[1][0]);
        acc[1][1] = mfma16(a1, b1, acc[1][1]);
    }
    for (int m = 0; m < 2; ++m)
        for (int n = 0; n < 2; ++n) {
            int e = e0 + wc + n * 16 + lr;
            int rbase = r0 + m * 16 + lg * 4;
            if (mat < 2) {
                unsigned short* dst = (mat == 0) ? Qb : Kb;
                for (int r = 0; r < 4; ++r)
                    dst[(size_t)(rbase + r) * 256 + e] = f2bf(acc[m][n][r]);
            } else {
                int bidx = rbase >> 13, nr = rbase & 8191;
                ushort4_t v;
                for (int r = 0; r < 4; ++r) v[r] = f2bf(acc[m][n][r]);
                *reinterpret_cast<ushort4_t*>(
                    Vt + ((size_t)bidx * 256 + e) * 8192 + nr) = v;
            }
        }
}

// ---------------------------------------------------------------------------
// Kernel 2: Z partials (R2/R1 version, proven).
// ---------------------------------------------------------------------------
__global__ __launch_bounds__(512) void k_zsum(
    const unsigned short* __restrict__ Qb, const unsigned short* __restrict__ Kb,
    float* __restrict__ Zpart)
{
    __shared__ unsigned short sK[64 * 256];
    __shared__ float zred[8][64];
    int qc = blockIdx.x, kt = blockIdx.y, b = blockIdx.z;
    int tid = threadIdx.x;

    for (int i = 0; i < 4; ++i) {
        int g = tid + i * 512;
        int r = g >> 5, c = g & 31;
        int off = (r * 512 + c * 16) ^ ((r & 7) << 4);
        *reinterpret_cast<short8*>(reinterpret_cast<char*>(sK) + off) =
            ldg8(Kb + (size_t)(b * N_ + kt * 64 + r) * 256 + c * 8);
    }
    __syncthreads();

    int w = tid >> 6, lane = tid & 63, lr = lane & 15, lg = lane >> 4;
    float zsum[4] = {0.f, 0.f, 0.f, 0.f};
    for (int it = 0; it < 32; ++it) {
        int qb = qc * 4096 + it * 128 + w * 16;
        const unsigned short* qrow = Qb + (size_t)(b * N_ + qb + lr) * 256;
        f32x4 acc[4] = {};
        for (int ks = 0; ks < 8; ++ks) {
            int d0 = ks * 32 + lg * 8;
            short8 a = ldg8(qrow + d0);
#pragma unroll
            for (int n = 0; n < 4; ++n) {
                int krow = n * 16 + lr;
                int off = (krow * 512 + d0 * 2) ^ ((krow & 7) << 4);
                short8 kb = *reinterpret_cast<const short8*>(
                    reinterpret_cast<const char*>(sK) + off);
                acc[n] = mfma16(a, kb, acc[n]);
            }
        }
#pragma unroll
        for (int n = 0; n < 4; ++n)
#pragma unroll
            for (int r = 0; r < 4; ++r)
                zsum[n] += __expf(acc[n][r] * SCALE);
    }
#pragma unroll
    for (int n = 0; n < 4; ++n) {
        float v = zsum[n];
        v += __shfl_xor(v, 16);
        v += __shfl_xor(v, 32);
        if (lg == 0) zred[w][n * 16 + lr] = v;
    }
    __syncthreads();
    if (tid < 64) {
        float s = 0.f;
        for (int ww = 0; ww < 8; ++ww) s += zred[ww][tid];
        Zpart[(size_t)(qc * 2 + b) * N_ + kt * 64 + tid] = s;
    }
}

__global__ void k_rz(const float* __restrict__ Zpart, float* __restrict__ rZ) {
    int t = blockIdx.x * 256 + threadIdx.x;  // 16384
    int b = t >> 13, k = t & 8191;
    float z = Zpart[(size_t)b * N_ + k] + Zpart[(size_t)(2 + b) * N_ + k];
    rZ[t] = 1.0f / z;
}

// ---------------------------------------------------------------------------
// Kernel 2.5: V' = V * rZ (in place on Vt, bf16).
// ---------------------------------------------------------------------------
__global__ __launch_bounds__(256) void k_scalev(
    unsigned short* __restrict__ Vt, const float* __restrict__ rZ)
{
    int t = blockIdx.x * 256 + threadIdx.x;
    int b = t >> 18, g = t & 262143;
    int d = g >> 10, k8 = (g & 1023) * 8;
    unsigned short* p = Vt + ((size_t)b * 256 + d) * 8192 + k8;
    short8 v = *reinterpret_cast<short8*>(p);
    const float* rz = rZ + (size_t)b * 8192 + k8;
    float4 r0 = *(const float4*)rz, r1 = *(const float4*)(rz + 4);
    float rv[8] = {r0.x, r0.y, r0.z, r0.w, r1.x, r1.y, r1.z, r1.w};
    short8 o;
#pragma unroll
    for (int j = 0; j < 8; ++j)
        o[j] = (short)f2bf(bf2f((unsigned short)v[j]) * rv[j]);
    *reinterpret_cast<short8*>(p) = o;
}

// ---------------------------------------------------------------------------
// Kernel 3 (v4): out[q,d] = sum_k exp(S[q,k]*SCALE) * V'[k,d].
// Grid (64 qt, NKH, 2 b), 512 thr (8 waves). qtile=128; each block sweeps
// nkt tiles of 64 k starting at blockIdx.y*nkt*64.
// Waves: 2 q-strips (64q) x 4 k-quarters (S) / d-quarters (PV).
// Per wave: S 64q x 16k, PV 64q x 64d. Q hoisted (128 VGPR), acc 64 VGPR.
// LDS: K dbuf 2x32K @0, V dbuf 2x32K @65536, P 16K @131072 = 144 KB.
// kh==0 writes out; kh==1 writes part (merged by k_add).
// ---------------------------------------------------------------------------
__global__ __launch_bounds__(512, 2) void k_attn(
    const unsigned short* __restrict__ Qb, const unsigned short* __restrict__ Kb,
    const unsigned short* __restrict__ Vt, float* __restrict__ out,
    float* __restrict__ part, int nkt)
{
    extern __shared__ char smem[];
    const int qt = blockIdx.x, kh = blockIdx.y, b = blockIdx.z;
    const int tid = threadIdx.x, w = tid >> 6, lane = tid & 63;
    const int lr = lane & 15, lg = lane >> 4;
    const int wqs = w >> 2, wq4 = w & 3;
    const int qbase = qt * 128, q0 = wqs * 64;
    const int k0 = kh * nkt * 64;

    // staging lane offsets (elements) within one 64k tile, pre-swizzled
    int koff[4], voff[4];
#pragma unroll
    for (int i = 0; i < 4; ++i) {
        int L = w * 256 + i * 64 + lane;
        int r = L >> 5, c = (L & 31) ^ (r & 7);
        koff[i] = r * 256 + c * 8;
        int d = L >> 3, c2 = (L & 7) ^ (d & 7);
        voff[i] = d * 8192 + c2 * 8;
    }
    const unsigned short* kbp = Kb + (size_t)(b * N_ + k0) * 256;
    const unsigned short* vbp = Vt + (size_t)b * 256 * 8192 + k0;

    // prologue: stage tile 0 -> buffer 0
#pragma unroll
    for (int i = 0; i < 4; ++i) {
        gll16(kbp + koff[i], smem + (size_t)(w * 256 + i * 64) * 16);
        gll16(vbp + voff[i], smem + 65536 + (size_t)(w * 256 + i * 64) * 16);
    }
    kbp += 64 * 256;
    vbp += 64;

    // hoist Q: 64 rows x 256 d (16 frags = 128 VGPR)
    short8 qfr[4][8];
#pragma unroll
    for (int qf = 0; qf < 4; ++qf) {
        const unsigned short* qrow =
            Qb + (size_t)(b * N_ + qbase + q0 + qf * 16 + lr) * 256;
#pragma unroll
        for (int ks = 0; ks < 8; ++ks)
            qfr[qf][ks] = ldg8(qrow + ks * 32 + lg * 8);
    }

    f32x4 acco[4][4] = {};

    for (int kt = 0; kt < nkt; ++kt) {
        const int cur = kt & 1;
        char* sK = smem + cur * 32768;
        char* sV = smem + 65536 + cur * 32768;
        char* sP = smem + 131072;

        WAIT_VM0();                  // staging of tile kt complete (own ops)
        BARRIER();                   // all waves' slices done
        __builtin_amdgcn_sched_barrier(0);

        if (kt + 1 < nkt) {
            char* nK = smem + (cur ^ 1) * 32768;
            char* nV = smem + 65536 + (cur ^ 1) * 32768;
#pragma unroll
            for (int i = 0; i < 4; ++i) {
                gll16(kbp + koff[i], nK + (size_t)(w * 256 + i * 64) * 16);
                gll16(vbp + voff[i], nV + (size_t)(w * 256 + i * 64) * 16);
            }
            kbp += 64 * 256;
            vbp += 64;
        }

        // ---- S phase: 64q x 16k ----
        f32x4 sacc[4] = {};
        __builtin_amdgcn_s_setprio(1);
#pragma unroll
        for (int ks = 0; ks < 8; ++ks) {
            int krow = wq4 * 16 + lr;
            int off = (krow * 512 + (ks * 32 + lg * 8) * 2) ^ ((krow & 7) << 4);
            short8 kbf = *reinterpret_cast<const short8*>(sK + off);
            sacc[0] = mfma16(qfr[0][ks], kbf, sacc[0]);
            sacc[1] = mfma16(qfr[1][ks], kbf, sacc[1]);
            sacc[2] = mfma16(qfr[2][ks], kbf, sacc[2]);
            sacc[3] = mfma16(qfr[3][ks], kbf, sacc[3]);
        }
        __builtin_amdgcn_s_setprio(0);

        // ---- P = exp(S*SCALE) -> LDS bf16 (swizzled) ----
#pragma unroll
        for (int qf = 0; qf < 4; ++qf)
#pragma unroll
            for (int r = 0; r < 4; ++r) {
                float p = __expf(sacc[qf][r] * SCALE);
                int q = q0 + qf * 16 + lg * 4 + r;
                int kcol = wq4 * 16 + lr;
                int off = (q * 128 + kcol * 2) ^ ((q & 7) << 4);
                *reinterpret_cast<unsigned short*>(sP + off) = f2bf(p);
            }

        WAIT_LGKM0();                // own P writes drained
        BARRIER();                   // all P visible
        __builtin_amdgcn_sched_barrier(0);

        // ---- PV phase: 64q x 64d over 64 k ----
        __builtin_amdgcn_s_setprio(1);
#pragma unroll
        for (int kk = 0; kk < 2; ++kk) {
            int coff = (kk * 32 + lg * 8) * 2;
            short8 pa[4];
#pragma unroll
            for (int qf = 0; qf < 4; ++qf) {
                int qq = q0 + qf * 16 + lr;
                pa[qf] = *reinterpret_cast<const short8*>(
                    sP + ((qq * 128 + coff) ^ ((qq & 7) << 4)));
            }
#pragma unroll
            for (int df = 0; df < 4; ++df) {
                int d = wq4 * 64 + df * 16 + lr;
                short8 vbf = *reinterpret_cast<const short8*>(
                    sV + ((d * 128 + coff) ^ ((d & 7) << 4)));
                acco[0][df] = mfma16(pa[0], vbf, acco[0][df]);
                acco[1][df] = mfma16(pa[1], vbf, acco[1][df]);
                acco[2][df] = mfma16(pa[2], vbf, acco[2][df]);
                acco[3][df] = mfma16(pa[3], vbf, acco[3][df]);
            }
        }
        __builtin_amdgcn_s_setprio(0);
    }

    // epilogue: f32 store to out (kh=0) or partial buffer (kh=1)
    float* dst = (kh == 0) ? out : part;
#pragma unroll
    for (int qf = 0; qf < 4; ++qf)
#pragma unroll
        for (int df = 0; df < 4; ++df) {
            int d = wq4 * 64 + df * 16 + lr;
            int qr = qbase + q0 + qf * 16 + lg * 4;
#pragma unroll
            for (int r = 0; r < 4; ++r)
                dst[(size_t)(b * N_ + qr + r) * 256 + d] = acco[qf][df][r];
        }
}

// out += part  (4.2M f32)
__global__ __launch_bounds__(256) void k_add(
    float* __restrict__ out, const float* __restrict__ part)
{
    int t = blockIdx.x * 256 + threadIdx.x;   // 1048576 float4 / 4 per thread
#pragma unroll
    for (int i = 0; i < 4; ++i) {
        int idx = t + i * 262144;
        float4 a = reinterpret_cast<float4*>(out)[idx];
        float4 p = reinterpret_cast<const float4*>(part)[idx];
        a.x += p.x; a.y += p.y; a.z += p.z; a.w += p.w;
        reinterpret_cast<float4*>(out)[idx] = a;
    }
}

extern "C" void kernel_launch(void* const* d_in, const int* in_sizes, int n_in,
                              void* d_out, int out_size, void* d_ws, size_t ws_size,
                              hipStream_t stream)
{
    const float* x  = (const float*)d_in[0];
    const float* Wq = (const float*)d_in[1];
    const float* Wk = (const float*)d_in[2];
    const float* Wv = (const float*)d_in[3];

    char* ws = (char*)d_ws;
    unsigned short* Qb = (unsigned short*)(ws);              //  8 MB
    unsigned short* Kb = (unsigned short*)(ws + 8388608);    //  8 MB
    unsigned short* Vt = (unsigned short*)(ws + 16777216);   //  8 MB
    float* Zpart       = (float*)(ws + 25165824);            // 256 KB
    float* rZ          = (float*)(ws + 25427968);            //  64 KB
    float* part1       = (float*)(ws + 25493504);            //  16 MB
    float* out = (float*)d_out;

    k_proj<<<dim3(256, 12), dim3(256), 0, stream>>>(x, Wq, Wk, Wv, Qb, Kb, Vt);
    k_zsum<<<dim3(2, 128, 2), dim3(512), 0, stream>>>(Qb, Kb, Zpart);
    k_rz<<<dim3(64), dim3(256), 0, stream>>>(Zpart, rZ);
    k_scalev<<<dim3(2048), dim3(256), 0, stream>>>(Vt, rZ);

    hipFuncSetAttribute((const void*)k_attn,
                        hipFuncAttributeMaxDynamicSharedMemorySize, 147456);
    if (ws_size >= (size_t)25493504 + 16777216) {
        // k-split: kh=0 -> out, kh=1 -> part1, then merge
        k_attn<<<dim3(64, 2, 2), dim3(512), 147456, stream>>>(
            Qb, Kb, Vt, out, part1, 64);
        k_add<<<dim3(1024), dim3(256), 0, stream>>>(out, part1);
    } else {
        // fallback: single block sweeps full k-range
        k_attn<<<dim3(64, 1, 2), dim3(512), 147456, stream>>>(
            Qb, Kb, Vt, out, out, 128);
    }
}

// Round 5
// 430.243 us; speedup vs baseline: 1.7218x; 1.1559x over previous
//
#include <hip/hip_runtime.h>
#include <hip/hip_bf16.h>

// Attention with softmax over the QUERY axis (axis=1):
//   attn[:,q,k] = exp(S[q,k]) / Z[k],  Z[k] = sum_q exp(S[q,k])
//   out = expS @ (diag(1/Z) V)   -- rZ folded into V by k_scalev.
// B=2, N=8192, D=256. All matmuls via mfma_f32_16x16x32_bf16.
// R5: R4 + launch_bounds(512,1) spill fix; proj reads x once via LDS staging.

#define N_ 8192
#define SCALE 0.0625f

typedef __attribute__((ext_vector_type(8))) short short8;
typedef __attribute__((ext_vector_type(4))) float f32x4;
typedef __attribute__((ext_vector_type(4))) unsigned short ushort4_t;

__device__ inline unsigned short f2bf(float f) {
    unsigned int x = __float_as_uint(f);
    unsigned int r = (x + 0x7fffu + ((x >> 16) & 1u)) >> 16;  // RNE
    return (unsigned short)r;
}

__device__ inline short8 ldg8(const unsigned short* p) {
    return *reinterpret_cast<const short8*>(p);
}

__device__ inline short8 cvt8(const float* p) {
    float4 a = *(const float4*)p;
    float4 b = *(const float4*)(p + 4);
    short8 r;
    r[0] = (short)f2bf(a.x); r[1] = (short)f2bf(a.y);
    r[2] = (short)f2bf(a.z); r[3] = (short)f2bf(a.w);
    r[4] = (short)f2bf(b.x); r[5] = (short)f2bf(b.y);
    r[6] = (short)f2bf(b.z); r[7] = (short)f2bf(b.w);
    return r;
}

__device__ inline f32x4 mfma16(short8 a, short8 b, f32x4 c) {
    return __builtin_amdgcn_mfma_f32_16x16x32_bf16(a, b, c, 0, 0, 0);
}

__device__ inline float bf2f(unsigned short u) {
    return __uint_as_float(((unsigned)u) << 16);
}

typedef __attribute__((address_space(3))) unsigned int lds_u32;
typedef __attribute__((address_space(1))) const unsigned int glb_u32;
__device__ __forceinline__ void gll16(const void* g, void* l) {
    __builtin_amdgcn_global_load_lds((glb_u32*)g, (lds_u32*)l, 16, 0, 0);
}
#define WAIT_VM0()   asm volatile("s_waitcnt vmcnt(0)" ::: "memory")
#define WAIT_LGKM0() asm volatile("s_waitcnt lgkmcnt(0)" ::: "memory")
#define BARRIER()    __builtin_amdgcn_s_barrier()

// ---------------------------------------------------------------------------
// Kernel 0: W (3 x 256x256 f32) -> Wb (768x256 bf16), concatenated Q|K|V.
// ---------------------------------------------------------------------------
__global__ __launch_bounds__(256) void k_cvtw(
    const float* __restrict__ Wq, const float* __restrict__ Wk,
    const float* __restrict__ Wv, unsigned short* __restrict__ Wb)
{
    int t = blockIdx.x * 256 + threadIdx.x;     // 24576 threads x 8 elems
    int e8 = t * 8;
    const float* src = (e8 < 65536) ? Wq + e8
                     : (e8 < 131072) ? Wk + (e8 - 65536)
                                     : Wv + (e8 - 131072);
    *reinterpret_cast<short8*>(Wb + e8) = cvt8(src);
}

// ---------------------------------------------------------------------------
// Kernel 1 (v2): QKV projection, x read ONCE. Grid 256 blocks (64 rows each),
// 512 thr (8 waves). x-tile 64x256 staged to LDS as bf16 (swizzled); each
// wave computes 64 rows x 96 cols, Wb streamed from L2.
// Q,K -> [b*N+r][256] bf16; V -> transposed Vt[b][e][n] bf16.
// ---------------------------------------------------------------------------
__global__ __launch_bounds__(512) void k_proj(
    const float* __restrict__ x, const unsigned short* __restrict__ Wb,
    unsigned short* __restrict__ Qb, unsigned short* __restrict__ Kb,
    unsigned short* __restrict__ Vt)
{
    __shared__ unsigned short sX[64 * 256];   // 32 KB, XOR-swizzled
    int rb = blockIdx.x;
    int tid = threadIdx.x, w = tid >> 6, lane = tid & 63;
    int lr = lane & 15, lg = lane >> 4;

    // stage x tile (convert f32->bf16 once)
#pragma unroll
    for (int i = 0; i < 4; ++i) {
        int g = tid + i * 512;                 // 2048 granules of 8 elems
        int r = g >> 5, c = g & 31;
        int off = (r * 512 + c * 16) ^ ((r & 7) << 4);
        *reinterpret_cast<short8*>(reinterpret_cast<char*>(sX) + off) =
            cvt8(x + (size_t)(rb * 64 + r) * 256 + c * 8);
    }
    __syncthreads();

    f32x4 acc[4][6] = {};
#pragma unroll
    for (int ks = 0; ks < 8; ++ks) {
        int coff = (ks * 32 + lg * 8) * 2;
        short8 xf[4];
#pragma unroll
        for (int rf = 0; rf < 4; ++rf) {
            int row = rf * 16 + lr;
            int off = (row * 512 + coff) ^ ((row & 7) << 4);
            xf[rf] = *reinterpret_cast<const short8*>(
                reinterpret_cast<const char*>(sX) + off);
        }
#pragma unroll
        for (int cf = 0; cf < 6; ++cf) {
            int e = w * 96 + cf * 16 + lr;
            short8 bfr = ldg8(Wb + (size_t)e * 256 + ks * 32 + lg * 8);
#pragma unroll
            for (int rf = 0; rf < 4; ++rf)
                acc[rf][cf] = mfma16(xf[rf], bfr, acc[rf][cf]);
        }
    }

#pragma unroll
    for (int rf = 0; rf < 4; ++rf)
#pragma unroll
        for (int cf = 0; cf < 6; ++cf) {
            int e0c = w * 96 + cf * 16;       // tile-uniform
            int mat = e0c >> 8;               // 0:Q 1:K 2:V
            int ecol = (e0c & 255) + lr;
            int rbase = rb * 64 + rf * 16 + lg * 4;
            if (mat < 2) {
                unsigned short* dst = (mat == 0) ? Qb : Kb;
#pragma unroll
                for (int r = 0; r < 4; ++r)
                    dst[(size_t)(rbase + r) * 256 + ecol] = f2bf(acc[rf][cf][r]);
            } else {
                int bidx = rbase >> 13, nr = rbase & 8191;
                ushort4_t v;
#pragma unroll
                for (int r = 0; r < 4; ++r) v[r] = f2bf(acc[rf][cf][r]);
                *reinterpret_cast<ushort4_t*>(
                    Vt + ((size_t)bidx * 256 + ecol) * 8192 + nr) = v;
            }
        }
}

// ---------------------------------------------------------------------------
// Kernel 2: Z partials (proven R2 version).
// ---------------------------------------------------------------------------
__global__ __launch_bounds__(512) void k_zsum(
    const unsigned short* __restrict__ Qb, const unsigned short* __restrict__ Kb,
    float* __restrict__ Zpart)
{
    __shared__ unsigned short sK[64 * 256];
    __shared__ float zred[8][64];
    int qc = blockIdx.x, kt = blockIdx.y, b = blockIdx.z;
    int tid = threadIdx.x;

    for (int i = 0; i < 4; ++i) {
        int g = tid + i * 512;
        int r = g >> 5, c = g & 31;
        int off = (r * 512 + c * 16) ^ ((r & 7) << 4);
        *reinterpret_cast<short8*>(reinterpret_cast<char*>(sK) + off) =
            ldg8(Kb + (size_t)(b * N_ + kt * 64 + r) * 256 + c * 8);
    }
    __syncthreads();

    int w = tid >> 6, lane = tid & 63, lr = lane & 15, lg = lane >> 4;
    float zsum[4] = {0.f, 0.f, 0.f, 0.f};
    for (int it = 0; it < 32; ++it) {
        int qb = qc * 4096 + it * 128 + w * 16;
        const unsigned short* qrow = Qb + (size_t)(b * N_ + qb + lr) * 256;
        f32x4 acc[4] = {};
        for (int ks = 0; ks < 8; ++ks) {
            int d0 = ks * 32 + lg * 8;
            short8 a = ldg8(qrow + d0);
#pragma unroll
            for (int n = 0; n < 4; ++n) {
                int krow = n * 16 + lr;
                int off = (krow * 512 + d0 * 2) ^ ((krow & 7) << 4);
                short8 kb = *reinterpret_cast<const short8*>(
                    reinterpret_cast<const char*>(sK) + off);
                acc[n] = mfma16(a, kb, acc[n]);
            }
        }
#pragma unroll
        for (int n = 0; n < 4; ++n)
#pragma unroll
            for (int r = 0; r < 4; ++r)
                zsum[n] += __expf(acc[n][r] * SCALE);
    }
#pragma unroll
    for (int n = 0; n < 4; ++n) {
        float v = zsum[n];
        v += __shfl_xor(v, 16);
        v += __shfl_xor(v, 32);
        if (lg == 0) zred[w][n * 16 + lr] = v;
    }
    __syncthreads();
    if (tid < 64) {
        float s = 0.f;
        for (int ww = 0; ww < 8; ++ww) s += zred[ww][tid];
        Zpart[(size_t)(qc * 2 + b) * N_ + kt * 64 + tid] = s;
    }
}

__global__ void k_rz(const float* __restrict__ Zpart, float* __restrict__ rZ) {
    int t = blockIdx.x * 256 + threadIdx.x;  // 16384
    int b = t >> 13, k = t & 8191;
    float z = Zpart[(size_t)b * N_ + k] + Zpart[(size_t)(2 + b) * N_ + k];
    rZ[t] = 1.0f / z;
}

// ---------------------------------------------------------------------------
// Kernel 2.5: V' = V * rZ (in place on Vt, bf16).
// ---------------------------------------------------------------------------
__global__ __launch_bounds__(256) void k_scalev(
    unsigned short* __restrict__ Vt, const float* __restrict__ rZ)
{
    int t = blockIdx.x * 256 + threadIdx.x;
    int b = t >> 18, g = t & 262143;
    int d = g >> 10, k8 = (g & 1023) * 8;
    unsigned short* p = Vt + ((size_t)b * 256 + d) * 8192 + k8;
    short8 v = *reinterpret_cast<short8*>(p);
    const float* rz = rZ + (size_t)b * 8192 + k8;
    float4 r0 = *(const float4*)rz, r1 = *(const float4*)(rz + 4);
    float rv[8] = {r0.x, r0.y, r0.z, r0.w, r1.x, r1.y, r1.z, r1.w};
    short8 o;
#pragma unroll
    for (int j = 0; j < 8; ++j)
        o[j] = (short)f2bf(bf2f((unsigned short)v[j]) * rv[j]);
    *reinterpret_cast<short8*>(p) = o;
}

// ---------------------------------------------------------------------------
// Kernel 3: out[q,d] = sum_k exp(S[q,k]*SCALE) * V'[k,d].
// Grid (64 qt, NKH, 2 b), 512 thr (8 waves). qtile=128; nkt tiles of 64 k
// starting at kh*nkt*64. Per wave: S 64q x 16k, PV 64q x 64d.
// Q hoisted (128 VGPR), acco 64 VGPR. launch_bounds(512,1): VGPR cap 256,
// 1 block/CU (LDS 144 KB anyway). kh==0 -> out, kh==1 -> part (k_add merges).
// ---------------------------------------------------------------------------
__global__ __launch_bounds__(512, 1) void k_attn(
    const unsigned short* __restrict__ Qb, const unsigned short* __restrict__ Kb,
    const unsigned short* __restrict__ Vt, float* __restrict__ out,
    float* __restrict__ part, int nkt)
{
    extern __shared__ char smem[];
    const int qt = blockIdx.x, kh = blockIdx.y, b = blockIdx.z;
    const int tid = threadIdx.x, w = tid >> 6, lane = tid & 63;
    const int lr = lane & 15, lg = lane >> 4;
    const int wqs = w >> 2, wq4 = w & 3;
    const int qbase = qt * 128, q0 = wqs * 64;
    const int k0 = kh * nkt * 64;

    // staging lane offsets (elements) within one 64k tile, pre-swizzled
    int koff[4], voff[4];
#pragma unroll
    for (int i = 0; i < 4; ++i) {
        int L = w * 256 + i * 64 + lane;
        int r = L >> 5, c = (L & 31) ^ (r & 7);
        koff[i] = r * 256 + c * 8;
        int d = L >> 3, c2 = (L & 7) ^ (d & 7);
        voff[i] = d * 8192 + c2 * 8;
    }
    const unsigned short* kbp = Kb + (size_t)(b * N_ + k0) * 256;
    const unsigned short* vbp = Vt + (size_t)b * 256 * 8192 + k0;

    // prologue: stage tile 0 -> buffer 0
#pragma unroll
    for (int i = 0; i < 4; ++i) {
        gll16(kbp + koff[i], smem + (size_t)(w * 256 + i * 64) * 16);
        gll16(vbp + voff[i], smem + 65536 + (size_t)(w * 256 + i * 64) * 16);
    }
    kbp += 64 * 256;
    vbp += 64;

    // hoist Q: 64 rows x 256 d (16 frags = 128 VGPR)
    short8 qfr[4][8];
#pragma unroll
    for (int qf = 0; qf < 4; ++qf) {
        const unsigned short* qrow =
            Qb + (size_t)(b * N_ + qbase + q0 + qf * 16 + lr) * 256;
#pragma unroll
        for (int ks = 0; ks < 8; ++ks)
            qfr[qf][ks] = ldg8(qrow + ks * 32 + lg * 8);
    }

    f32x4 acco[4][4] = {};

    for (int kt = 0; kt < nkt; ++kt) {
        const int cur = kt & 1;
        char* sK = smem + cur * 32768;
        char* sV = smem + 65536 + cur * 32768;
        char* sP = smem + 131072;

        WAIT_VM0();                  // staging of tile kt complete (own ops)
        BARRIER();                   // all waves' slices done
        __builtin_amdgcn_sched_barrier(0);

        if (kt + 1 < nkt) {
            char* nK = smem + (cur ^ 1) * 32768;
            char* nV = smem + 65536 + (cur ^ 1) * 32768;
#pragma unroll
            for (int i = 0; i < 4; ++i) {
                gll16(kbp + koff[i], nK + (size_t)(w * 256 + i * 64) * 16);
                gll16(vbp + voff[i], nV + (size_t)(w * 256 + i * 64) * 16);
            }
            kbp += 64 * 256;
            vbp += 64;
        }

        // ---- S phase: 64q x 16k ----
        f32x4 sacc[4] = {};
        __builtin_amdgcn_s_setprio(1);
#pragma unroll
        for (int ks = 0; ks < 8; ++ks) {
            int krow = wq4 * 16 + lr;
            int off = (krow * 512 + (ks * 32 + lg * 8) * 2) ^ ((krow & 7) << 4);
            short8 kbf = *reinterpret_cast<const short8*>(sK + off);
            sacc[0] = mfma16(qfr[0][ks], kbf, sacc[0]);
            sacc[1] = mfma16(qfr[1][ks], kbf, sacc[1]);
            sacc[2] = mfma16(qfr[2][ks], kbf, sacc[2]);
            sacc[3] = mfma16(qfr[3][ks], kbf, sacc[3]);
        }
        __builtin_amdgcn_s_setprio(0);

        // ---- P = exp(S*SCALE) -> LDS bf16 (swizzled) ----
#pragma unroll
        for (int qf = 0; qf < 4; ++qf)
#pragma unroll
            for (int r = 0; r < 4; ++r) {
                float p = __expf(sacc[qf][r] * SCALE);
                int q = q0 + qf * 16 + lg * 4 + r;
                int kcol = wq4 * 16 + lr;
                int off = (q * 128 + kcol * 2) ^ ((q & 7) << 4);
                *reinterpret_cast<unsigned short*>(sP + off) = f2bf(p);
            }

        WAIT_LGKM0();                // own P writes drained
        BARRIER();                   // all P visible
        __builtin_amdgcn_sched_barrier(0);

        // ---- PV phase: 64q x 64d over 64 k ----
        __builtin_amdgcn_s_setprio(1);
#pragma unroll
        for (int kk = 0; kk < 2; ++kk) {
            int coff = (kk * 32 + lg * 8) * 2;
            short8 pa[4];
#pragma unroll
            for (int qf = 0; qf < 4; ++qf) {
                int qq = q0 + qf * 16 + lr;
                pa[qf] = *reinterpret_cast<const short8*>(
                    sP + ((qq * 128 + coff) ^ ((qq & 7) << 4)));
            }
#pragma unroll
            for (int df = 0; df < 4; ++df) {
                int d = wq4 * 64 + df * 16 + lr;
                short8 vbf = *reinterpret_cast<const short8*>(
                    sV + ((d * 128 + coff) ^ ((d & 7) << 4)));
                acco[0][df] = mfma16(pa[0], vbf, acco[0][df]);
                acco[1][df] = mfma16(pa[1], vbf, acco[1][df]);
                acco[2][df] = mfma16(pa[2], vbf, acco[2][df]);
                acco[3][df] = mfma16(pa[3], vbf, acco[3][df]);
            }
        }
        __builtin_amdgcn_s_setprio(0);
    }

    // epilogue: f32 store to out (kh=0) or partial buffer (kh=1)
    float* dst = (kh == 0) ? out : part;
#pragma unroll
    for (int qf = 0; qf < 4; ++qf)
#pragma unroll
        for (int df = 0; df < 4; ++df) {
            int d = wq4 * 64 + df * 16 + lr;
            int qr = qbase + q0 + qf * 16 + lg * 4;
#pragma unroll
            for (int r = 0; r < 4; ++r)
                dst[(size_t)(b * N_ + qr + r) * 256 + d] = acco[qf][df][r];
        }
}

// out += part  (4.2M f32)
__global__ __launch_bounds__(256) void k_add(
    float* __restrict__ out, const float* __restrict__ part)
{
    int t = blockIdx.x * 256 + threadIdx.x;
#pragma unroll
    for (int i = 0; i < 4; ++i) {
        int idx = t + i * 262144;
        float4 a = reinterpret_cast<float4*>(out)[idx];
        float4 p = reinterpret_cast<const float4*>(part)[idx];
        a.x += p.x; a.y += p.y; a.z += p.z; a.w += p.w;
        reinterpret_cast<float4*>(out)[idx] = a;
    }
}

extern "C" void kernel_launch(void* const* d_in, const int* in_sizes, int n_in,
                              void* d_out, int out_size, void* d_ws, size_t ws_size,
                              hipStream_t stream)
{
    const float* x  = (const float*)d_in[0];
    const float* Wq = (const float*)d_in[1];
    const float* Wk = (const float*)d_in[2];
    const float* Wv = (const float*)d_in[3];

    char* ws = (char*)d_ws;
    unsigned short* Qb = (unsigned short*)(ws);              //  8 MB
    unsigned short* Kb = (unsigned short*)(ws + 8388608);    //  8 MB
    unsigned short* Vt = (unsigned short*)(ws + 16777216);   //  8 MB
    float* Zpart       = (float*)(ws + 25165824);            // 256 KB
    float* rZ          = (float*)(ws + 25427968);            //  64 KB
    unsigned short* Wb = (unsigned short*)(ws + 25493504);   // 384 KB
    float* part1       = (float*)(ws + 25886720);            //  16 MB
    float* out = (float*)d_out;

    k_cvtw<<<dim3(96), dim3(256), 0, stream>>>(Wq, Wk, Wv, Wb);
    k_proj<<<dim3(256), dim3(512), 0, stream>>>(x, Wb, Qb, Kb, Vt);
    k_zsum<<<dim3(2, 128, 2), dim3(512), 0, stream>>>(Qb, Kb, Zpart);
    k_rz<<<dim3(64), dim3(256), 0, stream>>>(Zpart, rZ);
    k_scalev<<<dim3(2048), dim3(256), 0, stream>>>(Vt, rZ);

    hipFuncSetAttribute((const void*)k_attn,
                        hipFuncAttributeMaxDynamicSharedMemorySize, 147456);
    if (ws_size >= (size_t)25886720 + 16777216) {
        k_attn<<<dim3(64, 2, 2), dim3(512), 147456, stream>>>(
            Qb, Kb, Vt, out, part1, 64);
        k_add<<<dim3(1024), dim3(256), 0, stream>>>(out, part1);
    } else {
        k_attn<<<dim3(64, 1, 2), dim3(512), 147456, stream>>>(
            Qb, Kb, Vt, out, out, 128);
    }
}

// Round 6
// 407.143 us; speedup vs baseline: 1.8195x; 1.0567x over previous
//
#include <hip/hip_runtime.h>
#include <hip/hip_bf16.h>

// Attention with softmax over the QUERY axis (axis=1):
//   attn[:,q,k] = exp(S[q,k]) / Z[k],  Z[k] = sum_q exp(S[q,k])
//   out = expS @ (diag(1/Z) V)   -- rZ folded into V by k_scalev.
// B=2, N=8192, D=256. All matmuls via mfma_f32_16x16x32_bf16.
// R6: pin hoisted Q/K fragments with asm "+v" so the compiler cannot sink the
// global loads back into the loop (VGPR_Count 88..128 across R2-R5 proved it
// was re-fetching Q from L2 inside every iteration).

#define N_ 8192
#define SCALE 0.0625f

typedef __attribute__((ext_vector_type(8))) short short8;
typedef __attribute__((ext_vector_type(4))) float f32x4;
typedef __attribute__((ext_vector_type(4))) unsigned short ushort4_t;

__device__ inline unsigned short f2bf(float f) {
    unsigned int x = __float_as_uint(f);
    unsigned int r = (x + 0x7fffu + ((x >> 16) & 1u)) >> 16;  // RNE
    return (unsigned short)r;
}

__device__ inline short8 ldg8(const unsigned short* p) {
    return *reinterpret_cast<const short8*>(p);
}

__device__ inline short8 cvt8(const float* p) {
    float4 a = *(const float4*)p;
    float4 b = *(const float4*)(p + 4);
    short8 r;
    r[0] = (short)f2bf(a.x); r[1] = (short)f2bf(a.y);
    r[2] = (short)f2bf(a.z); r[3] = (short)f2bf(a.w);
    r[4] = (short)f2bf(b.x); r[5] = (short)f2bf(b.y);
    r[6] = (short)f2bf(b.z); r[7] = (short)f2bf(b.w);
    return r;
}

__device__ inline f32x4 mfma16(short8 a, short8 b, f32x4 c) {
    return __builtin_amdgcn_mfma_f32_16x16x32_bf16(a, b, c, 0, 0, 0);
}

__device__ inline float bf2f(unsigned short u) {
    return __uint_as_float(((unsigned)u) << 16);
}

// Pin a fragment into VGPRs: asm-defined values cannot be rematerialized by
// re-loading from memory, so the allocator must keep them resident.
#define PIN8(v) asm volatile("" : "+v"(v))

typedef __attribute__((address_space(3))) unsigned int lds_u32;
typedef __attribute__((address_space(1))) const unsigned int glb_u32;
__device__ __forceinline__ void gll16(const void* g, void* l) {
    __builtin_amdgcn_global_load_lds((glb_u32*)g, (lds_u32*)l, 16, 0, 0);
}
#define WAIT_VM0()   asm volatile("s_waitcnt vmcnt(0)" ::: "memory")
#define WAIT_LGKM0() asm volatile("s_waitcnt lgkmcnt(0)" ::: "memory")
#define BARRIER()    __builtin_amdgcn_s_barrier()

// ---------------------------------------------------------------------------
// Kernel 0: W (3 x 256x256 f32) -> Wb (768x256 bf16), concatenated Q|K|V.
// ---------------------------------------------------------------------------
__global__ __launch_bounds__(256) void k_cvtw(
    const float* __restrict__ Wq, const float* __restrict__ Wk,
    const float* __restrict__ Wv, unsigned short* __restrict__ Wb)
{
    int t = blockIdx.x * 256 + threadIdx.x;     // 24576 threads x 8 elems
    int e8 = t * 8;
    const float* src = (e8 < 65536) ? Wq + e8
                     : (e8 < 131072) ? Wk + (e8 - 65536)
                                     : Wv + (e8 - 131072);
    *reinterpret_cast<short8*>(Wb + e8) = cvt8(src);
}

// ---------------------------------------------------------------------------
// Kernel 1 (v2): QKV projection, x read ONCE (proven R5).
// ---------------------------------------------------------------------------
__global__ __launch_bounds__(512) void k_proj(
    const float* __restrict__ x, const unsigned short* __restrict__ Wb,
    unsigned short* __restrict__ Qb, unsigned short* __restrict__ Kb,
    unsigned short* __restrict__ Vt)
{
    __shared__ unsigned short sX[64 * 256];   // 32 KB, XOR-swizzled
    int rb = blockIdx.x;
    int tid = threadIdx.x, w = tid >> 6, lane = tid & 63;
    int lr = lane & 15, lg = lane >> 4;

#pragma unroll
    for (int i = 0; i < 4; ++i) {
        int g = tid + i * 512;
        int r = g >> 5, c = g & 31;
        int off = (r * 512 + c * 16) ^ ((r & 7) << 4);
        *reinterpret_cast<short8*>(reinterpret_cast<char*>(sX) + off) =
            cvt8(x + (size_t)(rb * 64 + r) * 256 + c * 8);
    }
    __syncthreads();

    f32x4 acc[4][6] = {};
#pragma unroll
    for (int ks = 0; ks < 8; ++ks) {
        int coff = (ks * 32 + lg * 8) * 2;
        short8 xf[4];
#pragma unroll
        for (int rf = 0; rf < 4; ++rf) {
            int row = rf * 16 + lr;
            int off = (row * 512 + coff) ^ ((row & 7) << 4);
            xf[rf] = *reinterpret_cast<const short8*>(
                reinterpret_cast<const char*>(sX) + off);
        }
#pragma unroll
        for (int cf = 0; cf < 6; ++cf) {
            int e = w * 96 + cf * 16 + lr;
            short8 bfr = ldg8(Wb + (size_t)e * 256 + ks * 32 + lg * 8);
#pragma unroll
            for (int rf = 0; rf < 4; ++rf)
                acc[rf][cf] = mfma16(xf[rf], bfr, acc[rf][cf]);
        }
    }

#pragma unroll
    for (int rf = 0; rf < 4; ++rf)
#pragma unroll
        for (int cf = 0; cf < 6; ++cf) {
            int e0c = w * 96 + cf * 16;
            int mat = e0c >> 8;               // 0:Q 1:K 2:V
            int ecol = (e0c & 255) + lr;
            int rbase = rb * 64 + rf * 16 + lg * 4;
            if (mat < 2) {
                unsigned short* dst = (mat == 0) ? Qb : Kb;
#pragma unroll
                for (int r = 0; r < 4; ++r)
                    dst[(size_t)(rbase + r) * 256 + ecol] = f2bf(acc[rf][cf][r]);
            } else {
                int bidx = rbase >> 13, nr = rbase & 8191;
                ushort4_t v;
#pragma unroll
                for (int r = 0; r < 4; ++r) v[r] = f2bf(acc[rf][cf][r]);
                *reinterpret_cast<ushort4_t*>(
                    Vt + ((size_t)bidx * 256 + ecol) * 8192 + nr) = v;
            }
        }
}

// ---------------------------------------------------------------------------
// Kernel 2: Z partials. R2 skeleton + PIN on hoisted K tile.
// ---------------------------------------------------------------------------
__global__ __launch_bounds__(512) void k_zsum(
    const unsigned short* __restrict__ Qb, const unsigned short* __restrict__ Kb,
    float* __restrict__ Zpart)
{
    __shared__ unsigned short sK[64 * 256];
    __shared__ float zred[8][64];
    int qc = blockIdx.x, kt = blockIdx.y, b = blockIdx.z;
    int tid = threadIdx.x;

    for (int i = 0; i < 4; ++i) {
        int g = tid + i * 512;
        int r = g >> 5, c = g & 31;
        int off = (r * 512 + c * 16) ^ ((r & 7) << 4);
        *reinterpret_cast<short8*>(reinterpret_cast<char*>(sK) + off) =
            ldg8(Kb + (size_t)(b * N_ + kt * 64 + r) * 256 + c * 8);
    }
    __syncthreads();

    int w = tid >> 6, lane = tid & 63, lr = lane & 15, lg = lane >> 4;

    // hoist this wave's K fragments from LDS once, pin them
    short8 kfr[4][8];
#pragma unroll
    for (int n = 0; n < 4; ++n)
#pragma unroll
        for (int ks = 0; ks < 8; ++ks) {
            int krow = n * 16 + lr;
            int off = (krow * 512 + (ks * 32 + lg * 8) * 2) ^ ((krow & 7) << 4);
            kfr[n][ks] = *reinterpret_cast<const short8*>(
                reinterpret_cast<const char*>(sK) + off);
            PIN8(kfr[n][ks]);
        }

    float zsum[4] = {0.f, 0.f, 0.f, 0.f};
    for (int it = 0; it < 32; ++it) {
        int qb = qc * 4096 + it * 128 + w * 16;
        const unsigned short* qrow = Qb + (size_t)(b * N_ + qb + lr) * 256;
        f32x4 acc[4] = {};
        for (int ks = 0; ks < 8; ++ks) {
            int d0 = ks * 32 + lg * 8;
            short8 a = ldg8(qrow + d0);
#pragma unroll
            for (int n = 0; n < 4; ++n)
                acc[n] = mfma16(a, kfr[n][ks], acc[n]);
        }
#pragma unroll
        for (int n = 0; n < 4; ++n)
#pragma unroll
            for (int r = 0; r < 4; ++r)
                zsum[n] += __expf(acc[n][r] * SCALE);
    }
#pragma unroll
    for (int n = 0; n < 4; ++n) {
        float v = zsum[n];
        v += __shfl_xor(v, 16);
        v += __shfl_xor(v, 32);
        if (lg == 0) zred[w][n * 16 + lr] = v;
    }
    __syncthreads();
    if (tid < 64) {
        float s = 0.f;
        for (int ww = 0; ww < 8; ++ww) s += zred[ww][tid];
        Zpart[(size_t)(qc * 2 + b) * N_ + kt * 64 + tid] = s;
    }
}

__global__ void k_rz(const float* __restrict__ Zpart, float* __restrict__ rZ) {
    int t = blockIdx.x * 256 + threadIdx.x;  // 16384
    int b = t >> 13, k = t & 8191;
    float z = Zpart[(size_t)b * N_ + k] + Zpart[(size_t)(2 + b) * N_ + k];
    rZ[t] = 1.0f / z;
}

// ---------------------------------------------------------------------------
// Kernel 2.5: V' = V * rZ (in place on Vt, bf16).
// ---------------------------------------------------------------------------
__global__ __launch_bounds__(256) void k_scalev(
    unsigned short* __restrict__ Vt, const float* __restrict__ rZ)
{
    int t = blockIdx.x * 256 + threadIdx.x;
    int b = t >> 18, g = t & 262143;
    int d = g >> 10, k8 = (g & 1023) * 8;
    unsigned short* p = Vt + ((size_t)b * 256 + d) * 8192 + k8;
    short8 v = *reinterpret_cast<short8*>(p);
    const float* rz = rZ + (size_t)b * 8192 + k8;
    float4 r0 = *(const float4*)rz, r1 = *(const float4*)(rz + 4);
    float rv[8] = {r0.x, r0.y, r0.z, r0.w, r1.x, r1.y, r1.z, r1.w};
    short8 o;
#pragma unroll
    for (int j = 0; j < 8; ++j)
        o[j] = (short)f2bf(bf2f((unsigned short)v[j]) * rv[j]);
    *reinterpret_cast<short8*>(p) = o;
}

// ---------------------------------------------------------------------------
// Kernel 3: out[q,d] = sum_k exp(S[q,k]*SCALE) * V'[k,d].
// Grid (64 qt, NKH, 2 b), 512 thr (8 waves). qtile=128; nkt tiles of 64 k.
// Per wave: S 64q x 16k, PV 64q x 64d. Q hoisted AND PINNED (128 VGPR).
// LDS: K dbuf 2x32K @0, V dbuf 2x32K @65536, P 16K @131072 = 144 KB.
// ---------------------------------------------------------------------------
__global__ __launch_bounds__(512, 1) void k_attn(
    const unsigned short* __restrict__ Qb, const unsigned short* __restrict__ Kb,
    const unsigned short* __restrict__ Vt, float* __restrict__ out,
    float* __restrict__ part, int nkt)
{
    extern __shared__ char smem[];
    const int qt = blockIdx.x, kh = blockIdx.y, b = blockIdx.z;
    const int tid = threadIdx.x, w = tid >> 6, lane = tid & 63;
    const int lr = lane & 15, lg = lane >> 4;
    const int wqs = w >> 2, wq4 = w & 3;
    const int qbase = qt * 128, q0 = wqs * 64;
    const int k0 = kh * nkt * 64;

    // staging lane offsets (elements) within one 64k tile, pre-swizzled
    int koff[4], voff[4];
#pragma unroll
    for (int i = 0; i < 4; ++i) {
        int L = w * 256 + i * 64 + lane;
        int r = L >> 5, c = (L & 31) ^ (r & 7);
        koff[i] = r * 256 + c * 8;
        int d = L >> 3, c2 = (L & 7) ^ (d & 7);
        voff[i] = d * 8192 + c2 * 8;
    }
    const unsigned short* kbp = Kb + (size_t)(b * N_ + k0) * 256;
    const unsigned short* vbp = Vt + (size_t)b * 256 * 8192 + k0;

    // prologue: stage tile 0 -> buffer 0
#pragma unroll
    for (int i = 0; i < 4; ++i) {
        gll16(kbp + koff[i], smem + (size_t)(w * 256 + i * 64) * 16);
        gll16(vbp + voff[i], smem + 65536 + (size_t)(w * 256 + i * 64) * 16);
    }
    kbp += 64 * 256;
    vbp += 64;

    // hoist Q: 64 rows x 256 d (16 frags = 128 VGPR), PINNED so the compiler
    // cannot sink these loads into the loop (the R2-R5 latency anchor).
    short8 qfr[4][8];
#pragma unroll
    for (int qf = 0; qf < 4; ++qf) {
        const unsigned short* qrow =
            Qb + (size_t)(b * N_ + qbase + q0 + qf * 16 + lr) * 256;
#pragma unroll
        for (int ks = 0; ks < 8; ++ks) {
            qfr[qf][ks] = ldg8(qrow + ks * 32 + lg * 8);
            PIN8(qfr[qf][ks]);
        }
    }

    f32x4 acco[4][4] = {};

    for (int kt = 0; kt < nkt; ++kt) {
        const int cur = kt & 1;
        char* sK = smem + cur * 32768;
        char* sV = smem + 65536 + cur * 32768;
        char* sP = smem + 131072;

        WAIT_VM0();                  // staging of tile kt complete (own ops)
        BARRIER();                   // all waves' slices done
        __builtin_amdgcn_sched_barrier(0);

        if (kt + 1 < nkt) {
            char* nK = smem + (cur ^ 1) * 32768;
            char* nV = smem + 65536 + (cur ^ 1) * 32768;
#pragma unroll
            for (int i = 0; i < 4; ++i) {
                gll16(kbp + koff[i], nK + (size_t)(w * 256 + i * 64) * 16);
                gll16(vbp + voff[i], nV + (size_t)(w * 256 + i * 64) * 16);
            }
            kbp += 64 * 256;
            vbp += 64;
        }

        // ---- S phase: 64q x 16k ----
        f32x4 sacc[4] = {};
        __builtin_amdgcn_s_setprio(1);
#pragma unroll
        for (int ks = 0; ks < 8; ++ks) {
            int krow = wq4 * 16 + lr;
            int off = (krow * 512 + (ks * 32 + lg * 8) * 2) ^ ((krow & 7) << 4);
            short8 kbf = *reinterpret_cast<const short8*>(sK + off);
            sacc[0] = mfma16(qfr[0][ks], kbf, sacc[0]);
            sacc[1] = mfma16(qfr[1][ks], kbf, sacc[1]);
            sacc[2] = mfma16(qfr[2][ks], kbf, sacc[2]);
            sacc[3] = mfma16(qfr[3][ks], kbf, sacc[3]);
        }
        __builtin_amdgcn_s_setprio(0);

        // ---- P = exp(S*SCALE) -> LDS bf16 (swizzled) ----
#pragma unroll
        for (int qf = 0; qf < 4; ++qf)
#pragma unroll
            for (int r = 0; r < 4; ++r) {
                float p = __expf(sacc[qf][r] * SCALE);
                int q = q0 + qf * 16 + lg * 4 + r;
                int kcol = wq4 * 16 + lr;
                int off = (q * 128 + kcol * 2) ^ ((q & 7) << 4);
                *reinterpret_cast<unsigned short*>(sP + off) = f2bf(p);
            }

        WAIT_LGKM0();                // own P writes drained
        BARRIER();                   // all P visible
        __builtin_amdgcn_sched_barrier(0);

        // ---- PV phase: 64q x 64d over 64 k ----
        __builtin_amdgcn_s_setprio(1);
#pragma unroll
        for (int kk = 0; kk < 2; ++kk) {
            int coff = (kk * 32 + lg * 8) * 2;
            short8 pa[4];
#pragma unroll
            for (int qf = 0; qf < 4; ++qf) {
                int qq = q0 + qf * 16 + lr;
                pa[qf] = *reinterpret_cast<const short8*>(
                    sP + ((qq * 128 + coff) ^ ((qq & 7) << 4)));
            }
#pragma unroll
            for (int df = 0; df < 4; ++df) {
                int d = wq4 * 64 + df * 16 + lr;
                short8 vbf = *reinterpret_cast<const short8*>(
                    sV + ((d * 128 + coff) ^ ((d & 7) << 4)));
                acco[0][df] = mfma16(pa[0], vbf, acco[0][df]);
                acco[1][df] = mfma16(pa[1], vbf, acco[1][df]);
                acco[2][df] = mfma16(pa[2], vbf, acco[2][df]);
                acco[3][df] = mfma16(pa[3], vbf, acco[3][df]);
            }
        }
        __builtin_amdgcn_s_setprio(0);
    }

    // epilogue: f32 store to out (kh=0) or partial buffer (kh=1)
    float* dst = (kh == 0) ? out : part;
#pragma unroll
    for (int qf = 0; qf < 4; ++qf)
#pragma unroll
        for (int df = 0; df < 4; ++df) {
            int d = wq4 * 64 + df * 16 + lr;
            int qr = qbase + q0 + qf * 16 + lg * 4;
#pragma unroll
            for (int r = 0; r < 4; ++r)
                dst[(size_t)(b * N_ + qr + r) * 256 + d] = acco[qf][df][r];
        }
}

// out += part  (4.2M f32)
__global__ __launch_bounds__(256) void k_add(
    float* __restrict__ out, const float* __restrict__ part)
{
    int t = blockIdx.x * 256 + threadIdx.x;
#pragma unroll
    for (int i = 0; i < 4; ++i) {
        int idx = t + i * 262144;
        float4 a = reinterpret_cast<float4*>(out)[idx];
        float4 p = reinterpret_cast<const float4*>(part)[idx];
        a.x += p.x; a.y += p.y; a.z += p.z; a.w += p.w;
        reinterpret_cast<float4*>(out)[idx] = a;
    }
}

extern "C" void kernel_launch(void* const* d_in, const int* in_sizes, int n_in,
                              void* d_out, int out_size, void* d_ws, size_t ws_size,
                              hipStream_t stream)
{
    const float* x  = (const float*)d_in[0];
    const float* Wq = (const float*)d_in[1];
    const float* Wk = (const float*)d_in[2];
    const float* Wv = (const float*)d_in[3];

    char* ws = (char*)d_ws;
    unsigned short* Qb = (unsigned short*)(ws);              //  8 MB
    unsigned short* Kb = (unsigned short*)(ws + 8388608);    //  8 MB
    unsigned short* Vt = (unsigned short*)(ws + 16777216);   //  8 MB
    float* Zpart       = (float*)(ws + 25165824);            // 256 KB
    float* rZ          = (float*)(ws + 25427968);            //  64 KB
    unsigned short* Wb = (unsigned short*)(ws + 25493504);   // 384 KB
    float* part1       = (float*)(ws + 25886720);            //  16 MB
    float* out = (float*)d_out;

    k_cvtw<<<dim3(96), dim3(256), 0, stream>>>(Wq, Wk, Wv, Wb);
    k_proj<<<dim3(256), dim3(512), 0, stream>>>(x, Wb, Qb, Kb, Vt);
    k_zsum<<<dim3(2, 128, 2), dim3(512), 0, stream>>>(Qb, Kb, Zpart);
    k_rz<<<dim3(64), dim3(256), 0, stream>>>(Zpart, rZ);
    k_scalev<<<dim3(2048), dim3(256), 0, stream>>>(Vt, rZ);

    hipFuncSetAttribute((const void*)k_attn,
                        hipFuncAttributeMaxDynamicSharedMemorySize, 147456);
    if (ws_size >= (size_t)25886720 + 16777216) {
        k_attn<<<dim3(64, 2, 2), dim3(512), 147456, stream>>>(
            Qb, Kb, Vt, out, part1, 64);
        k_add<<<dim3(1024), dim3(256), 0, stream>>>(out, part1);
    } else {
        k_attn<<<dim3(64, 1, 2), dim3(512), 147456, stream>>>(
            Qb, Kb, Vt, out, out, 128);
    }
}

// Round 7
// 390.236 us; speedup vs baseline: 1.8983x; 1.0433x over previous
//
#include <hip/hip_runtime.h>
#include <hip/hip_bf16.h>

// Attention with softmax over the QUERY axis (axis=1):
//   attn[:,q,k] = exp(S[q,k]) / Z[k],  Z[k] = sum_q exp(S[q,k])
//   out = expS @ (diag(1/Z) V)   -- rZ folded into V by k_scalev.
// B=2, N=8192, D=256. All matmuls via mfma_f32_16x16x32_bf16.
// R7: amdgpu_waves_per_eu(2,2) on k_attn/k_zsum. R2-R6 all showed
// VGPR_Count==128 (the 4-waves/EU operating point) with ~240 live registers:
// the allocator targets an occupancy our 144KB LDS precludes, spilling ~112
// VGPRs. Capping the occupancy assumption at the real value (2 waves/EU)
// raises the budget to 256 and should eliminate the spill.

#define N_ 8192
#define SCALE 0.0625f

typedef __attribute__((ext_vector_type(8))) short short8;
typedef __attribute__((ext_vector_type(4))) float f32x4;
typedef __attribute__((ext_vector_type(4))) unsigned short ushort4_t;

__device__ inline unsigned short f2bf(float f) {
    unsigned int x = __float_as_uint(f);
    unsigned int r = (x + 0x7fffu + ((x >> 16) & 1u)) >> 16;  // RNE
    return (unsigned short)r;
}

__device__ inline short8 ldg8(const unsigned short* p) {
    return *reinterpret_cast<const short8*>(p);
}

__device__ inline short8 cvt8(const float* p) {
    float4 a = *(const float4*)p;
    float4 b = *(const float4*)(p + 4);
    short8 r;
    r[0] = (short)f2bf(a.x); r[1] = (short)f2bf(a.y);
    r[2] = (short)f2bf(a.z); r[3] = (short)f2bf(a.w);
    r[4] = (short)f2bf(b.x); r[5] = (short)f2bf(b.y);
    r[6] = (short)f2bf(b.z); r[7] = (short)f2bf(b.w);
    return r;
}

__device__ inline f32x4 mfma16(short8 a, short8 b, f32x4 c) {
    return __builtin_amdgcn_mfma_f32_16x16x32_bf16(a, b, c, 0, 0, 0);
}

__device__ inline float bf2f(unsigned short u) {
    return __uint_as_float(((unsigned)u) << 16);
}

// Pin a fragment into VGPRs at this program point.
#define PIN8(v) asm volatile("" : "+v"(v))

typedef __attribute__((address_space(3))) unsigned int lds_u32;
typedef __attribute__((address_space(1))) const unsigned int glb_u32;
__device__ __forceinline__ void gll16(const void* g, void* l) {
    __builtin_amdgcn_global_load_lds((glb_u32*)g, (lds_u32*)l, 16, 0, 0);
}
#define WAIT_VM0()   asm volatile("s_waitcnt vmcnt(0)" ::: "memory")
#define WAIT_LGKM0() asm volatile("s_waitcnt lgkmcnt(0)" ::: "memory")
#define BARRIER()    __builtin_amdgcn_s_barrier()

// ---------------------------------------------------------------------------
// Kernel 0: W (3 x 256x256 f32) -> Wb (768x256 bf16), concatenated Q|K|V.
// ---------------------------------------------------------------------------
__global__ __launch_bounds__(256) void k_cvtw(
    const float* __restrict__ Wq, const float* __restrict__ Wk,
    const float* __restrict__ Wv, unsigned short* __restrict__ Wb)
{
    int t = blockIdx.x * 256 + threadIdx.x;     // 24576 threads x 8 elems
    int e8 = t * 8;
    const float* src = (e8 < 65536) ? Wq + e8
                     : (e8 < 131072) ? Wk + (e8 - 65536)
                                     : Wv + (e8 - 131072);
    *reinterpret_cast<short8*>(Wb + e8) = cvt8(src);
}

// ---------------------------------------------------------------------------
// Kernel 1 (v2): QKV projection, x read ONCE (proven R5).
// ---------------------------------------------------------------------------
__global__ __launch_bounds__(512) void k_proj(
    const float* __restrict__ x, const unsigned short* __restrict__ Wb,
    unsigned short* __restrict__ Qb, unsigned short* __restrict__ Kb,
    unsigned short* __restrict__ Vt)
{
    __shared__ unsigned short sX[64 * 256];   // 32 KB, XOR-swizzled
    int rb = blockIdx.x;
    int tid = threadIdx.x, w = tid >> 6, lane = tid & 63;
    int lr = lane & 15, lg = lane >> 4;

#pragma unroll
    for (int i = 0; i < 4; ++i) {
        int g = tid + i * 512;
        int r = g >> 5, c = g & 31;
        int off = (r * 512 + c * 16) ^ ((r & 7) << 4);
        *reinterpret_cast<short8*>(reinterpret_cast<char*>(sX) + off) =
            cvt8(x + (size_t)(rb * 64 + r) * 256 + c * 8);
    }
    __syncthreads();

    f32x4 acc[4][6] = {};
#pragma unroll
    for (int ks = 0; ks < 8; ++ks) {
        int coff = (ks * 32 + lg * 8) * 2;
        short8 xf[4];
#pragma unroll
        for (int rf = 0; rf < 4; ++rf) {
            int row = rf * 16 + lr;
            int off = (row * 512 + coff) ^ ((row & 7) << 4);
            xf[rf] = *reinterpret_cast<const short8*>(
                reinterpret_cast<const char*>(sX) + off);
        }
#pragma unroll
        for (int cf = 0; cf < 6; ++cf) {
            int e = w * 96 + cf * 16 + lr;
            short8 bfr = ldg8(Wb + (size_t)e * 256 + ks * 32 + lg * 8);
#pragma unroll
            for (int rf = 0; rf < 4; ++rf)
                acc[rf][cf] = mfma16(xf[rf], bfr, acc[rf][cf]);
        }
    }

#pragma unroll
    for (int rf = 0; rf < 4; ++rf)
#pragma unroll
        for (int cf = 0; cf < 6; ++cf) {
            int e0c = w * 96 + cf * 16;
            int mat = e0c >> 8;               // 0:Q 1:K 2:V
            int ecol = (e0c & 255) + lr;
            int rbase = rb * 64 + rf * 16 + lg * 4;
            if (mat < 2) {
                unsigned short* dst = (mat == 0) ? Qb : Kb;
#pragma unroll
                for (int r = 0; r < 4; ++r)
                    dst[(size_t)(rbase + r) * 256 + ecol] = f2bf(acc[rf][cf][r]);
            } else {
                int bidx = rbase >> 13, nr = rbase & 8191;
                ushort4_t v;
#pragma unroll
                for (int r = 0; r < 4; ++r) v[r] = f2bf(acc[rf][cf][r]);
                *reinterpret_cast<ushort4_t*>(
                    Vt + ((size_t)bidx * 256 + ecol) * 8192 + nr) = v;
            }
        }
}

// ---------------------------------------------------------------------------
// Kernel 2: Z partials. R6 + waves_per_eu(2,2) so the 160 live VGPRs
// (kfr 128 + acc 16 + misc) fit without spill.
// ---------------------------------------------------------------------------
__global__
__attribute__((amdgpu_flat_work_group_size(512, 512), amdgpu_waves_per_eu(2, 2)))
void k_zsum(
    const unsigned short* __restrict__ Qb, const unsigned short* __restrict__ Kb,
    float* __restrict__ Zpart)
{
    __shared__ unsigned short sK[64 * 256];
    __shared__ float zred[8][64];
    int qc = blockIdx.x, kt = blockIdx.y, b = blockIdx.z;
    int tid = threadIdx.x;

    for (int i = 0; i < 4; ++i) {
        int g = tid + i * 512;
        int r = g >> 5, c = g & 31;
        int off = (r * 512 + c * 16) ^ ((r & 7) << 4);
        *reinterpret_cast<short8*>(reinterpret_cast<char*>(sK) + off) =
            ldg8(Kb + (size_t)(b * N_ + kt * 64 + r) * 256 + c * 8);
    }
    __syncthreads();

    int w = tid >> 6, lane = tid & 63, lr = lane & 15, lg = lane >> 4;

    // hoist this wave's K fragments from LDS once, pin them
    short8 kfr[4][8];
#pragma unroll
    for (int n = 0; n < 4; ++n)
#pragma unroll
        for (int ks = 0; ks < 8; ++ks) {
            int krow = n * 16 + lr;
            int off = (krow * 512 + (ks * 32 + lg * 8) * 2) ^ ((krow & 7) << 4);
            kfr[n][ks] = *reinterpret_cast<const short8*>(
                reinterpret_cast<const char*>(sK) + off);
            PIN8(kfr[n][ks]);
        }

    float zsum[4] = {0.f, 0.f, 0.f, 0.f};
    for (int it = 0; it < 32; ++it) {
        int qb = qc * 4096 + it * 128 + w * 16;
        const unsigned short* qrow = Qb + (size_t)(b * N_ + qb + lr) * 256;
        f32x4 acc[4] = {};
        for (int ks = 0; ks < 8; ++ks) {
            int d0 = ks * 32 + lg * 8;
            short8 a = ldg8(qrow + d0);
#pragma unroll
            for (int n = 0; n < 4; ++n)
                acc[n] = mfma16(a, kfr[n][ks], acc[n]);
        }
#pragma unroll
        for (int n = 0; n < 4; ++n)
#pragma unroll
            for (int r = 0; r < 4; ++r)
                zsum[n] += __expf(acc[n][r] * SCALE);
    }
#pragma unroll
    for (int n = 0; n < 4; ++n) {
        float v = zsum[n];
        v += __shfl_xor(v, 16);
        v += __shfl_xor(v, 32);
        if (lg == 0) zred[w][n * 16 + lr] = v;
    }
    __syncthreads();
    if (tid < 64) {
        float s = 0.f;
        for (int ww = 0; ww < 8; ++ww) s += zred[ww][tid];
        Zpart[(size_t)(qc * 2 + b) * N_ + kt * 64 + tid] = s;
    }
}

__global__ void k_rz(const float* __restrict__ Zpart, float* __restrict__ rZ) {
    int t = blockIdx.x * 256 + threadIdx.x;  // 16384
    int b = t >> 13, k = t & 8191;
    float z = Zpart[(size_t)b * N_ + k] + Zpart[(size_t)(2 + b) * N_ + k];
    rZ[t] = 1.0f / z;
}

// ---------------------------------------------------------------------------
// Kernel 2.5: V' = V * rZ (in place on Vt, bf16).
// ---------------------------------------------------------------------------
__global__ __launch_bounds__(256) void k_scalev(
    unsigned short* __restrict__ Vt, const float* __restrict__ rZ)
{
    int t = blockIdx.x * 256 + threadIdx.x;
    int b = t >> 18, g = t & 262143;
    int d = g >> 10, k8 = (g & 1023) * 8;
    unsigned short* p = Vt + ((size_t)b * 256 + d) * 8192 + k8;
    short8 v = *reinterpret_cast<short8*>(p);
    const float* rz = rZ + (size_t)b * 8192 + k8;
    float4 r0 = *(const float4*)rz, r1 = *(const float4*)(rz + 4);
    float rv[8] = {r0.x, r0.y, r0.z, r0.w, r1.x, r1.y, r1.z, r1.w};
    short8 o;
#pragma unroll
    for (int j = 0; j < 8; ++j)
        o[j] = (short)f2bf(bf2f((unsigned short)v[j]) * rv[j]);
    *reinterpret_cast<short8*>(p) = o;
}

// ---------------------------------------------------------------------------
// Kernel 3: out[q,d] = sum_k exp(S[q,k]*SCALE) * V'[k,d].
// Grid (64 qt, NKH, 2 b), 512 thr (8 waves). qtile=128; nkt tiles of 64 k.
// Per wave: S 64q x 16k, PV 64q x 64d. Q hoisted+pinned (128 VGPR),
// acco 64 VGPR. waves_per_eu(2,2): VGPR budget 256 -> ~240 live fits,
// no spill (R2-R6 were capped at 128 and spilled).
// LDS: K dbuf 2x32K @0, V dbuf 2x32K @65536, P 16K @131072 = 144 KB.
// ---------------------------------------------------------------------------
__global__
__attribute__((amdgpu_flat_work_group_size(512, 512), amdgpu_waves_per_eu(2, 2)))
void k_attn(
    const unsigned short* __restrict__ Qb, const unsigned short* __restrict__ Kb,
    const unsigned short* __restrict__ Vt, float* __restrict__ out,
    float* __restrict__ part, int nkt)
{
    extern __shared__ char smem[];
    const int qt = blockIdx.x, kh = blockIdx.y, b = blockIdx.z;
    const int tid = threadIdx.x, w = tid >> 6, lane = tid & 63;
    const int lr = lane & 15, lg = lane >> 4;
    const int wqs = w >> 2, wq4 = w & 3;
    const int qbase = qt * 128, q0 = wqs * 64;
    const int k0 = kh * nkt * 64;

    // staging lane offsets (elements) within one 64k tile, pre-swizzled
    int koff[4], voff[4];
#pragma unroll
    for (int i = 0; i < 4; ++i) {
        int L = w * 256 + i * 64 + lane;
        int r = L >> 5, c = (L & 31) ^ (r & 7);
        koff[i] = r * 256 + c * 8;
        int d = L >> 3, c2 = (L & 7) ^ (d & 7);
        voff[i] = d * 8192 + c2 * 8;
    }
    const unsigned short* kbp = Kb + (size_t)(b * N_ + k0) * 256;
    const unsigned short* vbp = Vt + (size_t)b * 256 * 8192 + k0;

    // prologue: stage tile 0 -> buffer 0
#pragma unroll
    for (int i = 0; i < 4; ++i) {
        gll16(kbp + koff[i], smem + (size_t)(w * 256 + i * 64) * 16);
        gll16(vbp + voff[i], smem + 65536 + (size_t)(w * 256 + i * 64) * 16);
    }
    kbp += 64 * 256;
    vbp += 64;

    // hoist Q: 64 rows x 256 d (16 frags = 128 VGPR), pinned
    short8 qfr[4][8];
#pragma unroll
    for (int qf = 0; qf < 4; ++qf) {
        const unsigned short* qrow =
            Qb + (size_t)(b * N_ + qbase + q0 + qf * 16 + lr) * 256;
#pragma unroll
        for (int ks = 0; ks < 8; ++ks) {
            qfr[qf][ks] = ldg8(qrow + ks * 32 + lg * 8);
            PIN8(qfr[qf][ks]);
        }
    }

    f32x4 acco[4][4] = {};

    for (int kt = 0; kt < nkt; ++kt) {
        const int cur = kt & 1;
        char* sK = smem + cur * 32768;
        char* sV = smem + 65536 + cur * 32768;
        char* sP = smem + 131072;

        WAIT_VM0();                  // staging of tile kt complete (own ops)
        BARRIER();                   // all waves' slices done
        __builtin_amdgcn_sched_barrier(0);

        if (kt + 1 < nkt) {
            char* nK = smem + (cur ^ 1) * 32768;
            char* nV = smem + 65536 + (cur ^ 1) * 32768;
#pragma unroll
            for (int i = 0; i < 4; ++i) {
                gll16(kbp + koff[i], nK + (size_t)(w * 256 + i * 64) * 16);
                gll16(vbp + voff[i], nV + (size_t)(w * 256 + i * 64) * 16);
            }
            kbp += 64 * 256;
            vbp += 64;
        }

        // ---- S phase: 64q x 16k ----
        f32x4 sacc[4] = {};
        __builtin_amdgcn_s_setprio(1);
#pragma unroll
        for (int ks = 0; ks < 8; ++ks) {
            int krow = wq4 * 16 + lr;
            int off = (krow * 512 + (ks * 32 + lg * 8) * 2) ^ ((krow & 7) << 4);
            short8 kbf = *reinterpret_cast<const short8*>(sK + off);
            sacc[0] = mfma16(qfr[0][ks], kbf, sacc[0]);
            sacc[1] = mfma16(qfr[1][ks], kbf, sacc[1]);
            sacc[2] = mfma16(qfr[2][ks], kbf, sacc[2]);
            sacc[3] = mfma16(qfr[3][ks], kbf, sacc[3]);
        }
        __builtin_amdgcn_s_setprio(0);

        // ---- P = exp(S*SCALE) -> LDS bf16 (swizzled) ----
#pragma unroll
        for (int qf = 0; qf < 4; ++qf)
#pragma unroll
            for (int r = 0; r < 4; ++r) {
                float p = __expf(sacc[qf][r] * SCALE);
                int q = q0 + qf * 16 + lg * 4 + r;
                int kcol = wq4 * 16 + lr;
                int off = (q * 128 + kcol * 2) ^ ((q & 7) << 4);
                *reinterpret_cast<unsigned short*>(sP + off) = f2bf(p);
            }

        WAIT_LGKM0();                // own P writes drained
        BARRIER();                   // all P visible
        __builtin_amdgcn_sched_barrier(0);

        // ---- PV phase: 64q x 64d over 64 k ----
        __builtin_amdgcn_s_setprio(1);
#pragma unroll
        for (int kk = 0; kk < 2; ++kk) {
            int coff = (kk * 32 + lg * 8) * 2;
            short8 pa[4];
#pragma unroll
            for (int qf = 0; qf < 4; ++qf) {
                int qq = q0 + qf * 16 + lr;
                pa[qf] = *reinterpret_cast<const short8*>(
                    sP + ((qq * 128 + coff) ^ ((qq & 7) << 4)));
            }
#pragma unroll
            for (int df = 0; df < 4; ++df) {
                int d = wq4 * 64 + df * 16 + lr;
                short8 vbf = *reinterpret_cast<const short8*>(
                    sV + ((d * 128 + coff) ^ ((d & 7) << 4)));
                acco[0][df] = mfma16(pa[0], vbf, acco[0][df]);
                acco[1][df] = mfma16(pa[1], vbf, acco[1][df]);
                acco[2][df] = mfma16(pa[2], vbf, acco[2][df]);
                acco[3][df] = mfma16(pa[3], vbf, acco[3][df]);
            }
        }
        __builtin_amdgcn_s_setprio(0);
    }

    // epilogue: f32 store to out (kh=0) or partial buffer (kh=1)
    float* dst = (kh == 0) ? out : part;
#pragma unroll
    for (int qf = 0; qf < 4; ++qf)
#pragma unroll
        for (int df = 0; df < 4; ++df) {
            int d = wq4 * 64 + df * 16 + lr;
            int qr = qbase + q0 + qf * 16 + lg * 4;
#pragma unroll
            for (int r = 0; r < 4; ++r)
                dst[(size_t)(b * N_ + qr + r) * 256 + d] = acco[qf][df][r];
        }
}

// out += part  (4.2M f32)
__global__ __launch_bounds__(256) void k_add(
    float* __restrict__ out, const float* __restrict__ part)
{
    int t = blockIdx.x * 256 + threadIdx.x;
#pragma unroll
    for (int i = 0; i < 4; ++i) {
        int idx = t + i * 262144;
        float4 a = reinterpret_cast<float4*>(out)[idx];
        float4 p = reinterpret_cast<const float4*>(part)[idx];
        a.x += p.x; a.y += p.y; a.z += p.z; a.w += p.w;
        reinterpret_cast<float4*>(out)[idx] = a;
    }
}

extern "C" void kernel_launch(void* const* d_in, const int* in_sizes, int n_in,
                              void* d_out, int out_size, void* d_ws, size_t ws_size,
                              hipStream_t stream)
{
    const float* x  = (const float*)d_in[0];
    const float* Wq = (const float*)d_in[1];
    const float* Wk = (const float*)d_in[2];
    const float* Wv = (const float*)d_in[3];

    char* ws = (char*)d_ws;
    unsigned short* Qb = (unsigned short*)(ws);              //  8 MB
    unsigned short* Kb = (unsigned short*)(ws + 8388608);    //  8 MB
    unsigned short* Vt = (unsigned short*)(ws + 16777216);   //  8 MB
    float* Zpart       = (float*)(ws + 25165824);            // 256 KB
    float* rZ          = (float*)(ws + 25427968);            //  64 KB
    unsigned short* Wb = (unsigned short*)(ws + 25493504);   // 384 KB
    float* part1       = (float*)(ws + 25886720);            //  16 MB
    float* out = (float*)d_out;

    k_cvtw<<<dim3(96), dim3(256), 0, stream>>>(Wq, Wk, Wv, Wb);
    k_proj<<<dim3(256), dim3(512), 0, stream>>>(x, Wb, Qb, Kb, Vt);
    k_zsum<<<dim3(2, 128, 2), dim3(512), 0, stream>>>(Qb, Kb, Zpart);
    k_rz<<<dim3(64), dim3(256), 0, stream>>>(Zpart, rZ);
    k_scalev<<<dim3(2048), dim3(256), 0, stream>>>(Vt, rZ);

    hipFuncSetAttribute((const void*)k_attn,
                        hipFuncAttributeMaxDynamicSharedMemorySize, 147456);
    if (ws_size >= (size_t)25886720 + 16777216) {
        k_attn<<<dim3(64, 2, 2), dim3(512), 147456, stream>>>(
            Qb, Kb, Vt, out, part1, 64);
        k_add<<<dim3(1024), dim3(256), 0, stream>>>(out, part1);
    } else {
        k_attn<<<dim3(64, 1, 2), dim3(512), 147456, stream>>>(
            Qb, Kb, Vt, out, out, 128);
    }
}